// Round 5
// baseline (223.935 us; speedup 1.0000x reference)
//
#include <hip/hip_runtime.h>
#include <hip/hip_fp16.h>

#define N_NODES 200000
#define N_EDGES 4000000
#define N_GRAPHS 512
#define D 20
#define OUT 5

#define NB 1563          // buckets of 128 nodes: dst >> 7
#define NBP 1564         // padded to multiple of 4
#define NC 500           // edge chunks
#define CHUNK 8000       // NC*CHUNK == N_EDGES
#define MAX_EB 3072      // max edges/bucket (mean 2560, +10 sigma, Chernoff p<1e-17)
#define GMAX 8           // max graphs spanned by one 128-node bucket (typ. <= 3)

// ---------- P0: zero gsum ----------
__global__ void k_zero_gsum(float* gsum) {
    int i = blockIdx.x * blockDim.x + threadIdx.x;
    if (i < N_GRAPHS * D) gsum[i] = 0.f;
}

// ---------- P1: per-chunk bucket histogram (LDS atomics) ----------
__launch_bounds__(256)
__global__ void k_hist(const int* __restrict__ dst, int* __restrict__ hist_g) {
    __shared__ int h[NBP];
    int t = threadIdx.x;
    for (int j = t; j < NBP; j += 256) h[j] = 0;
    __syncthreads();
    int base = blockIdx.x * CHUNK;
    for (int k = t; k < CHUNK; k += 256) atomicAdd(&h[dst[base + k] >> 7], 1);
    __syncthreads();
    for (int j = t; j < NBP; j += 256) hist_g[blockIdx.x * NBP + j] = h[j];
}

// ---------- P2: exclusive scan of chunk-columns, 4 buckets per block ----------
__launch_bounds__(512)
__global__ void k_scan_col(int* __restrict__ hist_g, int* __restrict__ tot_g) {
    __shared__ int4 s[512];
    int t = threadIdx.x;
    int b0 = blockIdx.x * 4;
    int4 v = make_int4(0, 0, 0, 0);
    if (t < NC) v = *(const int4*)&hist_g[t * NBP + b0];
    s[t] = v;
    __syncthreads();
    for (int off = 1; off < 512; off <<= 1) {
        int4 a = make_int4(0, 0, 0, 0);
        if (t >= off) a = s[t - off];
        __syncthreads();
        s[t].x += a.x; s[t].y += a.y; s[t].z += a.z; s[t].w += a.w;
        __syncthreads();
    }
    if (t < NC) {
        int4 ex = s[t];
        ex.x -= v.x; ex.y -= v.y; ex.z -= v.z; ex.w -= v.w;
        *(int4*)&hist_g[t * NBP + b0] = ex;
    }
    if (t == 511) *(int4*)&tot_g[b0] = s[511];
}

// ---------- P3: exclusive scan of bucket totals (1 block, 7 rounds) ----------
__launch_bounds__(256)
__global__ void k_scan_tot(const int* __restrict__ tot_g, int* __restrict__ bucket_base) {
    __shared__ int s[256];
    __shared__ int carry;
    int t = threadIdx.x;
    if (t == 0) carry = 0;
    __syncthreads();
    for (int r = 0; r < 7; r++) {
        int i = r * 256 + t;
        int v = (i < NBP) ? tot_g[i] : 0;
        s[t] = v;
        __syncthreads();
        for (int off = 1; off < 256; off <<= 1) {
            int a = (t >= off) ? s[t - off] : 0;
            __syncthreads();
            s[t] += a;
            __syncthreads();
        }
        int c = carry;
        if (i < NBP) bucket_base[i] = c + s[t] - v;
        __syncthreads();
        if (t == 0) carry = c + s[255];
        __syncthreads();
    }
}

// ---------- P4: partition edges into bucket-contiguous ebuf (packed) ----------
__launch_bounds__(256)
__global__ void k_partition(const int* __restrict__ src, const int* __restrict__ dst,
                            const int* __restrict__ hist_g, const int* __restrict__ bucket_base,
                            int* __restrict__ ebuf) {
    __shared__ int cur[NBP];
    int t = threadIdx.x, c = blockIdx.x;
    for (int j = t; j < NBP; j += 256) cur[j] = hist_g[c * NBP + j] + bucket_base[j];
    __syncthreads();
    int base = c * CHUNK;
    for (int k = t; k < CHUNK; k += 256) {
        int d = dst[base + k];
        int sv = src[base + k];
        int b = d >> 7;
        int pos = atomicAdd(&cur[b], 1);
        ebuf[pos] = (sv << 7) | (d & 127);
    }
}

// ---------- P5: per-bucket degree -> offs; xh = f16(dinv * x) ----------
__launch_bounds__(256)
__global__ void k_count_xh(const int* __restrict__ ebuf, const int* __restrict__ bucket_base,
                           const float4* __restrict__ x4, int* __restrict__ offs_g,
                           uint2* __restrict__ xh2) {
    __shared__ int cnt[128];
    __shared__ int s[256];
    __shared__ float sdi[128];
    int b = blockIdx.x, t = threadIdx.x;
    int eb = bucket_base[b], ee = bucket_base[b + 1];
    if (t < 128) cnt[t] = 0;
    __syncthreads();
    for (int k = eb + t; k < ee; k += 256) atomicAdd(&cnt[ebuf[k] & 127], 1);
    __syncthreads();
    int nbn = N_NODES - (b << 7); if (nbn > 128) nbn = 128;
    int v = (t < 128) ? cnt[t] : 0;
    s[t] = v;
    __syncthreads();
    for (int off = 1; off < 256; off <<= 1) {
        int a = (t >= off) ? s[t - off] : 0;
        __syncthreads();
        s[t] += a;
        __syncthreads();
    }
    if (t < nbn) {
        int node = (b << 7) + t;
        offs_g[node] = eb + s[t] - v;
        sdi[t] = rsqrtf((float)(v + 1));
    }
    __syncthreads();
    int nw = nbn * 5;
    for (int j = t; j < nw; j += 256) {
        int vl = j / 5, q = j - vl * 5;
        int node = (b << 7) + vl;
        float4 xv = x4[(size_t)node * 5 + q];
        float di = sdi[vl];
        __half2 h0 = __float22half2_rn(make_float2(xv.x * di, xv.y * di));
        __half2 h1 = __float22half2_rn(make_float2(xv.z * di, xv.w * di));
        uint2 u;
        u.x = *(unsigned int*)&h0;
        u.y = *(unsigned int*)&h1;
        xh2[(size_t)node * 5 + q] = u;
    }
}

// ---------- P6: bucket CSR in LDS + gather + W1 matvec + relu + graph pool ----------
__launch_bounds__(256)
__global__ void k_gather_fused(const int* __restrict__ ebuf, const int* __restrict__ bucket_base,
                               const int* __restrict__ offs_g, const uint2* __restrict__ xh2,
                               const int* __restrict__ batch, const float* __restrict__ W1,
                               const float* __restrict__ b1, float* __restrict__ gsum) {
    __shared__ int loff[129];
    __shared__ int cur[128];
    __shared__ int lcsr[MAX_EB];
    __shared__ float w[D * D];
    __shared__ float wb[D];
    __shared__ float sagg[128][21];     // padded row: bank-conflict-free column reads
    __shared__ float lgsum[GMAX][D];
    int b = blockIdx.x, t = threadIdx.x;
    int eb = bucket_base[b], ee = bucket_base[b + 1];
    int n = ee - eb;
    int nbn = N_NODES - (b << 7); if (nbn > 128) nbn = 128;

    for (int j = t; j < D * D; j += 256) w[j] = W1[j];
    if (t < D) wb[t] = b1[t];
    if (t < GMAX * D) ((float*)lgsum)[t] = 0.f;
    if (t < nbn) {
        int o = offs_g[(b << 7) + t] - eb;
        loff[t] = o;
        cur[t] = o;
    }
    if (t == 0) loff[nbn] = n;
    __syncthreads();

    // build bucket CSR in LDS
    for (int k = t; k < n; k += 256) {
        int p = ebuf[eb + k];
        int pos = atomicAdd(&cur[p & 127], 1);
        if (pos < MAX_EB) lcsr[pos] = p >> 7;
    }
    __syncthreads();

    // gather: sagg[vl] = xh[v] + sum over in-neighbors xh[s]
    int nw = nbn * 5;
    for (int j = t; j < nw; j += 256) {
        int vl = j / 5, q = j - vl * 5;
        int node = (b << 7) + vl;
        uint2 u = xh2[(size_t)node * 5 + q];
        float2 a0 = __half22float2(*(__half2*)&u.x);
        float2 a1 = __half22float2(*(__half2*)&u.y);
        float accx = a0.x, accy = a0.y, accz = a1.x, accw = a1.y;
        int lo = loff[vl], hi = loff[vl + 1];
        if (hi > MAX_EB) hi = MAX_EB;
        if (lo > MAX_EB) lo = MAX_EB;
        for (int k = lo; k < hi; k++) {
            int sv = lcsr[k];
            uint2 m = xh2[(size_t)sv * 5 + q];
            float2 m0 = __half22float2(*(__half2*)&m.x);
            float2 m1 = __half22float2(*(__half2*)&m.y);
            accx += m0.x; accy += m0.y; accz += m1.x; accw += m1.y;
        }
        sagg[vl][q * 4 + 0] = accx;
        sagg[vl][q * 4 + 1] = accy;
        sagg[vl][q * 4 + 2] = accz;
        sagg[vl][q * 4 + 3] = accw;
    }
    __syncthreads();

    int g0 = batch[b << 7];
    int glast = batch[(b << 7) + nbn - 1];
    int gcnt = glast - g0 + 1;

    if (t < nbn) {
        int node = (b << 7) + t;
        float di = rsqrtf((float)(loff[t + 1] - loff[t] + 1));   // recompute dinv from degree
        int gi = batch[node] - g0;
        float pre[D];
        #pragma unroll
        for (int d = 0; d < D; d++) pre[d] = sagg[t][d];
        int t20 = t % D;
        bool fits = (gcnt <= GMAX);
        for (int jj = 0; jj < D; jj++) {
            int o = t20 + jj; if (o >= D) o -= D;
            float h = 0.f;
            #pragma unroll
            for (int d = 0; d < D; d++) h = fmaf(pre[d], w[d * D + o], h);
            h = fmaf(h, di, wb[o]);
            h = fmaxf(h, 0.f);
            if (fits) atomicAdd(&lgsum[gi][o], h);
            else atomicAdd(&gsum[(g0 + gi) * D + o], h);  // safety path, never in practice
        }
    }
    __syncthreads();
    if (gcnt <= GMAX && t < gcnt * D) {
        atomicAdd(&gsum[(g0 + t / D) * D + (t % D)], lgsum[t / D][t % D]);
    }
}

// ---------- P7: head: mean -> W_out -> softmax ----------
__launch_bounds__(64)
__global__ void k_head(const float* __restrict__ gsum, const int* __restrict__ batch,
                       const float* __restrict__ W_out, const float* __restrict__ b_out,
                       float* __restrict__ out) {
    __shared__ float wo[D * OUT];
    __shared__ float bo[OUT];
    int t = threadIdx.x;
    for (int j = t; j < D * OUT; j += 64) wo[j] = W_out[j];
    if (t < OUT) bo[t] = b_out[t];
    __syncthreads();
    int g = blockIdx.x * 64 + t;
    if (g >= N_GRAPHS) return;
    auto lb = [&](int key) {
        int lo = 0, hi = N_NODES;
        while (lo < hi) { int mid = (lo + hi) >> 1; if (batch[mid] < key) lo = mid + 1; else hi = mid; }
        return lo;
    };
    int cnt = lb(g + 1) - lb(g);
    float inv = 1.0f / fmaxf((float)cnt, 1.0f);
    float logits[OUT];
    #pragma unroll
    for (int o = 0; o < OUT; o++) logits[o] = bo[o];
    #pragma unroll
    for (int d = 0; d < D; d++) {
        float p = gsum[g * D + d] * inv;
        #pragma unroll
        for (int o = 0; o < OUT; o++) logits[o] = fmaf(p, wo[d * OUT + o], logits[o]);
    }
    float m = logits[0];
    #pragma unroll
    for (int o = 1; o < OUT; o++) m = fmaxf(m, logits[o]);
    float ex[OUT], sum = 0.f;
    #pragma unroll
    for (int o = 0; o < OUT; o++) { ex[o] = __expf(logits[o] - m); sum += ex[o]; }
    float isum = 1.0f / sum;
    #pragma unroll
    for (int o = 0; o < OUT; o++) out[g * OUT + o] = ex[o] * isum;
}

extern "C" void kernel_launch(void* const* d_in, const int* in_sizes, int n_in,
                              void* d_out, int out_size, void* d_ws, size_t ws_size,
                              hipStream_t stream) {
    const float* x     = (const float*)d_in[0];
    const int*   edge  = (const int*)d_in[1];
    const int*   batch = (const int*)d_in[2];
    const float* W1    = (const float*)d_in[3];
    const float* b1    = (const float*)d_in[4];
    const float* W_out = (const float*)d_in[5];
    const float* b_out = (const float*)d_in[6];
    float* out = (float*)d_out;

    const int* src = edge;
    const int* dst = edge + N_EDGES;
    char* ws = (char*)d_ws;

    // workspace layout (bytes), total 28.8 MB (ws_size >= 50.4 MB verified in R3):
    int*   hist_g      = (int*)(ws);                 // 500*1564*4 = 3,128,000
    int*   tot_g       = (int*)(ws + 3128000);       // 1564*4
    int*   bucket_base = (int*)(ws + 3136000);       // 1564*4 (covers index NB=1563)
    float* gsum        = (float*)(ws + 3144000);     // 512*20*4 = 40,960
    int*   offs_g      = (int*)(ws + 3200000);       // 800,000
    uint2* xh2         = (uint2*)(ws + 4800000);     // 8,000,000 (f16 rows, 40 B/node)
    int*   ebuf        = (int*)(ws + 12800000);      // 16,000,000

    k_zero_gsum<<<(N_GRAPHS * D + 255) / 256, 256, 0, stream>>>(gsum);
    k_hist<<<NC, 256, 0, stream>>>(dst, hist_g);
    k_scan_col<<<NBP / 4, 512, 0, stream>>>(hist_g, tot_g);
    k_scan_tot<<<1, 256, 0, stream>>>(tot_g, bucket_base);
    k_partition<<<NC, 256, 0, stream>>>(src, dst, hist_g, bucket_base, ebuf);
    k_count_xh<<<NB, 256, 0, stream>>>(ebuf, bucket_base, (const float4*)x, offs_g, xh2);
    k_gather_fused<<<NB, 256, 0, stream>>>(ebuf, bucket_base, offs_g, xh2, batch, W1, b1, gsum);
    k_head<<<(N_GRAPHS + 63) / 64, 64, 0, stream>>>(gsum, batch, W_out, b_out, out);
}